// Round 8
// baseline (1231.159 us; speedup 1.0000x reference)
//
#include <hip/hip_runtime.h>
#include <hip/hip_fp16.h>
#include <hip/hip_cooperative_groups.h>

// GCNConv + ReLU + global mean pool for MI355X (gfx950).
// Round 8: (a) revert aggregate to the proven 4-deep form (round-7's 8-deep
// unroll regressed ~30us by sum-of-parts analysis); (b) fuse zero+Wt+count+
// scan+fill+deg into ONE cooperative kernel with grid.sync — kills 5 launch
// gaps and keeps per-edge CSR positions in registers (no pos array traffic).

namespace cg = cooperative_groups;

#define REPS 8

typedef _Float16 f16;
typedef _Float16 half8 __attribute__((ext_vector_type(8)));
typedef float f32x4 __attribute__((ext_vector_type(4)));

// ---------- fused CSR build (cooperative, grid-synced) ----------
__global__ __launch_bounds__(256) void k_build(
    const int* __restrict__ ei, const float* __restrict__ ew,
    const float* __restrict__ W,
    int* __restrict__ cnt4, int* __restrict__ rp4, int* __restrict__ bsum,
    int2* __restrict__ srcval, float* __restrict__ dinv, f16* __restrict__ Wt,
    int N, int E, int M)
{
    cg::grid_group grid = cg::this_grid();
    __shared__ int wsum[4];
    __shared__ int sCarry;
    __shared__ float sdeg[256];
    __shared__ int srp[257];

    const int t = threadIdx.x;
    const int bid = blockIdx.x;
    const int NB = gridDim.x;
    const int NT = NB * 256;
    const int gid = bid * 256 + t;
    const int lane = t & 63, wid = t >> 6;

    // P0: zero cnt4 (int4) + W -> Wt (f16 [n][k])
    int M4 = M >> 2;
    for (int i = gid; i < M4; i += NT) ((int4*)cnt4)[i] = make_int4(0, 0, 0, 0);
    if (gid < 4096) {
        int n = gid >> 5, k = (gid & 31) * 4;
        union { f16 h[4]; uint2 u; } p;
#pragma unroll
        for (int j = 0; j < 4; ++j) p.h[j] = (f16)W[(k + j) * 128 + n];
        *(uint2*)&Wt[n * 128 + k] = p.u;
    }
    grid.sync();

    // P1: count; per-edge insertion position stays in registers
    int pos[4];
#pragma unroll
    for (int q = 0; q < 4; ++q) {
        int e = gid + q * NT;
        pos[q] = (e < E) ? atomicAdd(&cnt4[(e & (REPS - 1)) * N + ei[E + e]], 1) : 0;
    }
    grid.sync();

    // P2: per-256-chunk exclusive scan of counts (view order k = node*8+rep)
    int nb1 = (M + 255) >> 8;
    for (int cb = bid; cb < nb1; cb += NB) {
        int k = cb * 256 + t;
        int v = (k < M) ? cnt4[(k & (REPS - 1)) * N + (k >> 3)] : 0;
        int s = v;
#pragma unroll
        for (int o = 1; o < 64; o <<= 1) {
            int u = __shfl_up(s, o);
            if (lane >= o) s += u;
        }
        if (lane == 63) wsum[wid] = s;
        __syncthreads();
        int off = 0;
#pragma unroll
        for (int w2 = 0; w2 < 4; ++w2) if (w2 < wid) off += wsum[w2];
        if (k < M) rp4[k] = off + s - v;
        if (t == 255) bsum[cb] = off + s;
        __syncthreads();
    }
    grid.sync();

    // P3: block 0 scans bsum[0..nb1) with running carry
    if (bid == 0) {
        if (t == 0) sCarry = 0;
        __syncthreads();
        for (int base = 0; base < nb1; base += 256) {
            int i = base + t;
            int v = (i < nb1) ? bsum[i] : 0;
            int s = v;
#pragma unroll
            for (int o = 1; o < 64; o <<= 1) {
                int u = __shfl_up(s, o);
                if (lane >= o) s += u;
            }
            if (lane == 63) wsum[wid] = s;
            __syncthreads();
            int off = 0;
#pragma unroll
            for (int w2 = 0; w2 < 4; ++w2) if (w2 < wid) off += wsum[w2];
            int tot = wsum[0] + wsum[1] + wsum[2] + wsum[3];
            int c = sCarry;
            __syncthreads();
            if (i < nb1) bsum[i] = c + off + s - v;
            if (t == 0) sCarry = c + tot;
            __syncthreads();
        }
    }
    grid.sync();

    // P4: add chunk offsets
    for (int k = gid; k < M; k += NT) rp4[k] += bsum[k >> 8];
    if (gid == 0) rp4[M] = E;
    grid.sync();

    // P5: atomic-free fill using registered positions
#pragma unroll
    for (int q = 0; q < 4; ++q) {
        int e = gid + q * NT;
        if (e < E) {
            int row = ei[e], col = ei[E + e];
            int slot = rp4[col * REPS + (e & (REPS - 1))] + pos[q];
            srcval[slot] = make_int2(row, __float_as_int(ew[e]));
        }
    }
    grid.sync();

    // P6: weighted degree from CSR (coalesced + LDS atomics), dinv = rsqrt
    int nchunks = (N + 255) >> 8;
    for (int cb = bid; cb < nchunks; cb += NB) {
        int n0 = cb * 256;
        int nn = min(256, N - n0);
        sdeg[t] = 1.0f;                   // self-loop weight
        for (int i = t; i <= nn; i += 256) srp[i] = rp4[(n0 + i) * REPS];
        __syncthreads();
        int beg = srp[0], end = srp[nn];
        for (int j = beg + t; j < end; j += 256) {
            int2 sv = srcval[j];
            int lo = 0, hi = nn - 1;
            while (lo < hi) {
                int mid = (lo + hi + 1) >> 1;
                if (srp[mid] <= j) lo = mid; else hi = mid - 1;
            }
            atomicAdd(&sdeg[lo], __int_as_float(sv.y));
        }
        __syncthreads();
        if (t < nn) dinv[n0 + t] = rsqrtf(sdeg[t]);
        __syncthreads();
    }
}

// ---------- h' = dinv * (x @ W) -> fp16 via MFMA, 128x128 tile per block ----------
__global__ __launch_bounds__(256) void k_gemm(const float* __restrict__ x,
                                              const f16* __restrict__ Wt,
                                              const float* __restrict__ dinv,
                                              f16* __restrict__ hh, int N) {
    __shared__ f16 sX[128 * 136];   // pad 8 halves: 2-way (free) bank conflicts
    __shared__ f16 sW[128 * 136];
    int t = threadIdx.x;
    int row0 = blockIdx.x * 128;
#pragma unroll
    for (int it = 0; it < 8; ++it) {
        int i = t + 256 * it;
        int n = i >> 4, k8 = (i & 15) * 8;
        *(half8*)&sW[n * 136 + k8] = *(const half8*)&Wt[n * 128 + k8];
    }
#pragma unroll
    for (int it = 0; it < 16; ++it) {
        int i = t + 256 * it;
        int r = i >> 5, c4 = (i & 31) * 4;
        float4 xv = make_float4(0.f, 0.f, 0.f, 0.f);
        if (row0 + r < N) xv = *(const float4*)&x[(size_t)(row0 + r) * 128 + c4];
        union { f16 h[4]; uint2 u; } p;
        p.h[0] = (f16)xv.x; p.h[1] = (f16)xv.y; p.h[2] = (f16)xv.z; p.h[3] = (f16)xv.w;
        *(uint2*)&sX[r * 136 + c4] = p.u;
    }
    __syncthreads();

    int w = t >> 6, l = t & 63;
    int lm = l & 15, lg = l >> 4;
    f32x4 acc[2][8];
#pragma unroll
    for (int rt = 0; rt < 2; ++rt)
#pragma unroll
        for (int ct = 0; ct < 8; ++ct) acc[rt][ct] = (f32x4){0.f, 0.f, 0.f, 0.f};

    int arow = w * 32 + lm;
#pragma unroll
    for (int ks = 0; ks < 4; ++ks) {
        int ko = ks * 32 + lg * 8;        // K-bijection identical for A and B
        half8 a0 = *(const half8*)&sX[arow * 136 + ko];
        half8 a1 = *(const half8*)&sX[(arow + 16) * 136 + ko];
#pragma unroll
        for (int ct = 0; ct < 8; ++ct) {
            half8 bf = *(const half8*)&sW[(ct * 16 + lm) * 136 + ko];
            acc[0][ct] = __builtin_amdgcn_mfma_f32_16x16x32_f16(a0, bf, acc[0][ct], 0, 0, 0);
            acc[1][ct] = __builtin_amdgcn_mfma_f32_16x16x32_f16(a1, bf, acc[1][ct], 0, 0, 0);
        }
    }

    // epilogue: scale by dinv, repack through this wave's own sX rows
#pragma unroll
    for (int rt = 0; rt < 2; ++rt) {
#pragma unroll
        for (int r = 0; r < 4; ++r) {
            int lrow = w * 32 + rt * 16 + lg * 4 + r;   // D row = (lane>>4)*4 + reg
            int grow = row0 + lrow;
            float di = (grow < N) ? dinv[grow] : 0.f;
#pragma unroll
            for (int ct = 0; ct < 8; ++ct)
                sX[lrow * 136 + ct * 16 + lm] = (f16)(acc[rt][ct][r] * di);  // D col = lane&15
        }
    }
#pragma unroll
    for (int it = 0; it < 8; ++it) {
        int i = l + 64 * it;
        int lr = i >> 4, k8 = (i & 15) * 8;
        int grow = row0 + w * 32 + lr;
        if (grow < N)
            *(half8*)&hh[(size_t)grow * 128 + k8] =
                *(const half8*)&sX[(w * 32 + lr) * 136 + k8];
    }
}

// ---------- gather-aggregate: 1 wave/node, 2 dims/lane, 4-deep (proven) ----------
// out[i] = relu( dinv_i * ( sum_j w_j*h'[src_j] + h'_i ) + b ),  h' = dinv*h
__global__ __launch_bounds__(256) void k_aggregate(const int2* __restrict__ srcval,
                                                   const int* __restrict__ rp4,
                                                   const __half* __restrict__ hh,
                                                   const float* __restrict__ dinv,
                                                   const float* __restrict__ b,
                                                   float* __restrict__ out, int N) {
    int node = blockIdx.x * 4 + (threadIdx.x >> 6);
    if (node >= N) return;
    int lane = threadIdx.x & 63;
    int beg = rp4[node * REPS], end = rp4[(node + 1) * REPS];
    float2 acc0 = make_float2(0.f, 0.f);
    float2 acc1 = make_float2(0.f, 0.f);
    float2 acc2 = make_float2(0.f, 0.f);
    float2 acc3 = make_float2(0.f, 0.f);
    int j = beg;
    for (; j + 4 <= end; j += 4) {
        int2 m0 = srcval[j];
        int2 m1 = srcval[j + 1];
        int2 m2 = srcval[j + 2];
        int2 m3 = srcval[j + 3];
        float2 h0 = __half22float2(*(const __half2*)&hh[(size_t)m0.x * 128 + lane * 2]);
        float2 h1 = __half22float2(*(const __half2*)&hh[(size_t)m1.x * 128 + lane * 2]);
        float2 h2 = __half22float2(*(const __half2*)&hh[(size_t)m2.x * 128 + lane * 2]);
        float2 h3 = __half22float2(*(const __half2*)&hh[(size_t)m3.x * 128 + lane * 2]);
        float w0 = __int_as_float(m0.y), w1 = __int_as_float(m1.y);
        float w2 = __int_as_float(m2.y), w3 = __int_as_float(m3.y);
        acc0.x = fmaf(h0.x, w0, acc0.x); acc0.y = fmaf(h0.y, w0, acc0.y);
        acc1.x = fmaf(h1.x, w1, acc1.x); acc1.y = fmaf(h1.y, w1, acc1.y);
        acc2.x = fmaf(h2.x, w2, acc2.x); acc2.y = fmaf(h2.y, w2, acc2.y);
        acc3.x = fmaf(h3.x, w3, acc3.x); acc3.y = fmaf(h3.y, w3, acc3.y);
    }
    for (; j < end; ++j) {
        int2 m0 = srcval[j];
        float w0 = __int_as_float(m0.y);
        float2 h0 = __half22float2(*(const __half2*)&hh[(size_t)m0.x * 128 + lane * 2]);
        acc0.x = fmaf(h0.x, w0, acc0.x); acc0.y = fmaf(h0.y, w0, acc0.y);
    }
    acc0.x += acc1.x + acc2.x + acc3.x;
    acc0.y += acc1.y + acc2.y + acc3.y;
    float di = dinv[node];
    float2 hs = __half22float2(*(const __half2*)&hh[(size_t)node * 128 + lane * 2]);
    float2 bv = *(const float2*)&b[lane * 2];
    float2 v;
    v.x = fmaxf(fmaf(acc0.x + hs.x, di, bv.x), 0.f);
    v.y = fmaxf(fmaf(acc0.y + hs.y, di, bv.y), 0.f);
    *(float2*)&out[(size_t)node * 128 + lane * 2] = v;
}

// ---------- pool: one block per graph, bounds by binary search, no atomics ----------
__global__ __launch_bounds__(256) void k_pool(const float* __restrict__ out,
                                              const int* __restrict__ batch,
                                              float* __restrict__ pool, int N, int G) {
    __shared__ float sacc[256];
    __shared__ int bounds[2];
    int g = blockIdx.x;
    int t = threadIdx.x;
    if (t < 2) {
        int target = g + t;
        int lo = 0, hi = N;
        while (lo < hi) {
            int mid = (lo + hi) >> 1;
            if (batch[mid] < target) lo = mid + 1; else hi = mid;
        }
        bounds[t] = lo;
    }
    __syncthreads();
    int lo = bounds[0], hi = bounds[1];
    int d = t & 127, r = t >> 7;
    float s = 0.f;
    for (int n = lo + r; n < hi; n += 2)
        s += out[(size_t)n * 128 + d];
    sacc[t] = s;
    __syncthreads();
    if (t < 128) {
        float tot = sacc[t] + sacc[t + 128];
        pool[(size_t)g * 128 + t] = tot / fmaxf((float)(hi - lo), 1.0f);
    }
}

extern "C" void kernel_launch(void* const* d_in, const int* in_sizes, int n_in,
                              void* d_out, int out_size, void* d_ws, size_t ws_size,
                              hipStream_t stream) {
    const float* x     = (const float*)d_in[0];
    const int*   ei    = (const int*)d_in[1];
    const float* ew    = (const float*)d_in[2];
    const int*   batch = (const int*)d_in[3];
    const float* W     = (const float*)d_in[4];
    const float* b     = (const float*)d_in[5];

    int N = in_sizes[3];                  // 50000
    int E = in_sizes[2];                  // 800000
    int G = (out_size - N * 128) / 128;   // 500
    int M = N * REPS;
    int nb1 = (M + 255) / 256;

    float* out  = (float*)d_out;
    float* pool = out + (size_t)N * 128;

    // workspace layout (~23 MB; no pos array anymore)
    f16*    hh     = (f16*)d_ws;                        // N*128 f16   (12.8 MB)
    int2*   srcval = (int2*)(hh + (size_t)N * 128);     // E int2      (6.4 MB)
    float*  dinv   = (float*)(srcval + E);              // N f
    int*    cnt4   = (int*)(dinv + N);                  // 8N i        (1.6 MB)
    int*    rp4    = cnt4 + M;                          // 8N+1 i      (1.6 MB)
    int*    bsum   = rp4 + M + 1;                       // nb1 i
    f16*    Wt     = (f16*)(((uintptr_t)(bsum + nb1) + 15) & ~(uintptr_t)15);  // 32 KB

    // cooperative grid sizing (capture-safe queries)
    int maxb = 4, cus = 256;
    hipOccupancyMaxActiveBlocksPerMultiprocessor(&maxb, k_build, 256, 0);
    hipDeviceGetAttribute(&cus, hipDeviceAttributeMultiprocessorCount, 0);
    int NB = maxb * cus;
    if (NB > 2048) NB = 2048;
    if (NB < 1) NB = 1;

    void* args[] = {(void*)&ei, (void*)&ew, (void*)&W, (void*)&cnt4, (void*)&rp4,
                    (void*)&bsum, (void*)&srcval, (void*)&dinv, (void*)&Wt,
                    (void*)&N, (void*)&E, (void*)&M};
    hipLaunchCooperativeKernel((void*)k_build, dim3(NB), dim3(256), args, 0, stream);

    k_gemm<<<(N + 127) / 128, 256, 0, stream>>>(x, Wt, dinv, hh, N);
    k_aggregate<<<(N + 3) / 4, 256, 0, stream>>>(srcval, rp4, (const __half*)hh, dinv, b, out, N);
    k_pool<<<G, 256, 0, stream>>>(out, batch, pool, N, G);
}

// Round 9
// 153.142 us; speedup vs baseline: 8.0394x; 8.0394x over previous
//
#include <hip/hip_runtime.h>
#include <hip/hip_fp16.h>

// GCNConv + ReLU + global mean pool for MI355X (gfx950).
// Round 9: revert round-8's cooperative fusion (grid.sync cost ~170us each ->
// 1220us kernel). Back to round-7 pipeline with: custom k_init (zero+Wt),
// count/scan/fill/deg CSR build, MFMA fp16 GEMM, and a NEW split-wave
// aggregate: 2 edges per wave step (8B fp16 loads per lane, half-wave per
// edge) -> 8 independent gather chains in flight per wave.

#define REPS 8

typedef _Float16 f16;
typedef _Float16 half8 __attribute__((ext_vector_type(8)));
typedef _Float16 half4v __attribute__((ext_vector_type(4)));
typedef float f32x4 __attribute__((ext_vector_type(4)));

// ---------- fused init: zero cnt4 (int4 stores) + W -> Wt (f16 [n][k]) ----------
__global__ __launch_bounds__(256) void k_init(int* __restrict__ cnt4, int M4, int nzb,
                                              const float* __restrict__ W,
                                              f16* __restrict__ Wt) {
    int bid = blockIdx.x;
    int t = threadIdx.x;
    if (bid < nzb) {
        int i = bid * 256 + t;
        if (i < M4) ((int4*)cnt4)[i] = make_int4(0, 0, 0, 0);
    } else {
        int n = (bid - nzb) * 8 + (t >> 5);
        int k = (t & 31) * 4;
        union { f16 h[4]; uint2 u; } p;
#pragma unroll
        for (int j = 0; j < 4; ++j) p.h[j] = (f16)W[(k + j) * 128 + n];
        *(uint2*)&Wt[n * 128 + k] = p.u;
    }
}

// ---------- count + record insertion position (1 atomic/edge, 8-way spread) ----------
__global__ __launch_bounds__(256) void k_count_pos(const int* __restrict__ ei,
                                                   int* cnt4, int* __restrict__ pos,
                                                   int E, int N) {
    int e = blockIdx.x * 256 + threadIdx.x;
    if (e < E) pos[e] = atomicAdd(&cnt4[(e & (REPS - 1)) * N + ei[E + e]], 1);
}

// ---------- scan phase 1 over M=8N counts in view order k=(node*8+rep) ----------
__global__ __launch_bounds__(256) void k_scan1(const int* __restrict__ cnt4,
                                               int* __restrict__ rp4,
                                               int* __restrict__ bsum, int M, int N) {
    __shared__ int wsum[4];
    int t = threadIdx.x;
    int k = blockIdx.x * 256 + t;
    int v = 0;
    if (k < M) v = cnt4[(k & (REPS - 1)) * N + (k / REPS)];
    int lane = t & 63, wid = t >> 6;
    int s = v;
#pragma unroll
    for (int o = 1; o < 64; o <<= 1) {
        int u = __shfl_up(s, o);
        if (lane >= o) s += u;
    }
    if (lane == 63) wsum[wid] = s;
    __syncthreads();
    int off = 0;
#pragma unroll
    for (int w = 0; w < 4; ++w)
        if (w < wid) off += wsum[w];
    if (k < M) rp4[k] = off + s - v;      // block-local exclusive
    if (t == 255) bsum[blockIdx.x] = off + s;
}

// ---------- scan phase 2: each block reduces its own carry, adds ----------
__global__ __launch_bounds__(256) void k_scan3(int* __restrict__ rp4,
                                               const int* __restrict__ bsum,
                                               int M, int E) {
    __shared__ int wsum[4];
    int t = threadIdx.x;
    int bid = blockIdx.x;
    int s = 0;
    for (int j = t; j < bid; j += 256) s += bsum[j];
    int lane = t & 63, wid = t >> 6;
#pragma unroll
    for (int o = 1; o < 64; o <<= 1) s += __shfl_down(s, o);
    if (lane == 0) wsum[wid] = s;
    __syncthreads();
    int off = wsum[0] + wsum[1] + wsum[2] + wsum[3];
    int k = bid * 256 + t;
    if (k < M) rp4[k] += off;
    if (bid == 0 && t == 0) rp4[M] = E;   // grand total known analytically
}

// ---------- atomic-free bucket fill: srcval[slot] = (src row, raw w) ----------
__global__ __launch_bounds__(256) void k_fill(const int* __restrict__ ei,
                                              const float* __restrict__ ew,
                                              const int* __restrict__ rp4,
                                              const int* __restrict__ pos,
                                              int2* __restrict__ srcval, int E) {
    int e = blockIdx.x * 256 + threadIdx.x;
    if (e >= E) return;
    int row = ei[e];
    int col = ei[E + e];
    int slot = rp4[col * REPS + (e & (REPS - 1))] + pos[e];
    srcval[slot] = make_int2(row, __float_as_int(ew[e]));
}

// ---------- weighted degree from CSR (coalesced + LDS atomics), dinv=rsqrt ----------
__global__ __launch_bounds__(256) void k_deg_csr(const int* __restrict__ rp4,
                                                 const int2* __restrict__ srcval,
                                                 float* __restrict__ dinv, int N) {
    __shared__ float sdeg[256];
    __shared__ int srp[257];
    int t = threadIdx.x;
    int n0 = blockIdx.x * 256;
    int nn = min(256, N - n0);
    if (nn <= 0) return;
    sdeg[t] = 1.0f;                       // self-loop weight
    for (int i = t; i <= nn; i += 256) srp[i] = rp4[(n0 + i) * REPS];
    __syncthreads();
    int beg = srp[0], end = srp[nn];
    for (int j = beg + t; j < end; j += 256) {
        int2 sv = srcval[j];
        int lo = 0, hi = nn - 1;          // find node: srp[lo] <= j < srp[lo+1]
        while (lo < hi) {
            int mid = (lo + hi + 1) >> 1;
            if (srp[mid] <= j) lo = mid; else hi = mid - 1;
        }
        atomicAdd(&sdeg[lo], __int_as_float(sv.y));
    }
    __syncthreads();
    if (t < nn) dinv[n0 + t] = rsqrtf(sdeg[t]);   // deg >= 1 always
}

// ---------- h' = dinv * (x @ W) -> fp16 via MFMA, 128x128 tile per block ----------
__global__ __launch_bounds__(256) void k_gemm(const float* __restrict__ x,
                                              const f16* __restrict__ Wt,
                                              const float* __restrict__ dinv,
                                              f16* __restrict__ hh, int N) {
    __shared__ f16 sX[128 * 136];   // pad 8 halves: 2-way (free) bank conflicts
    __shared__ f16 sW[128 * 136];
    int t = threadIdx.x;
    int row0 = blockIdx.x * 128;
#pragma unroll
    for (int it = 0; it < 8; ++it) {
        int i = t + 256 * it;
        int n = i >> 4, k8 = (i & 15) * 8;
        *(half8*)&sW[n * 136 + k8] = *(const half8*)&Wt[n * 128 + k8];
    }
#pragma unroll
    for (int it = 0; it < 16; ++it) {
        int i = t + 256 * it;
        int r = i >> 5, c4 = (i & 31) * 4;
        float4 xv = make_float4(0.f, 0.f, 0.f, 0.f);
        if (row0 + r < N) xv = *(const float4*)&x[(size_t)(row0 + r) * 128 + c4];
        union { f16 h[4]; uint2 u; } p;
        p.h[0] = (f16)xv.x; p.h[1] = (f16)xv.y; p.h[2] = (f16)xv.z; p.h[3] = (f16)xv.w;
        *(uint2*)&sX[r * 136 + c4] = p.u;
    }
    __syncthreads();

    int w = t >> 6, l = t & 63;
    int lm = l & 15, lg = l >> 4;
    f32x4 acc[2][8];
#pragma unroll
    for (int rt = 0; rt < 2; ++rt)
#pragma unroll
        for (int ct = 0; ct < 8; ++ct) acc[rt][ct] = (f32x4){0.f, 0.f, 0.f, 0.f};

    int arow = w * 32 + lm;
#pragma unroll
    for (int ks = 0; ks < 4; ++ks) {
        int ko = ks * 32 + lg * 8;        // K-bijection identical for A and B
        half8 a0 = *(const half8*)&sX[arow * 136 + ko];
        half8 a1 = *(const half8*)&sX[(arow + 16) * 136 + ko];
#pragma unroll
        for (int ct = 0; ct < 8; ++ct) {
            half8 bf = *(const half8*)&sW[(ct * 16 + lm) * 136 + ko];
            acc[0][ct] = __builtin_amdgcn_mfma_f32_16x16x32_f16(a0, bf, acc[0][ct], 0, 0, 0);
            acc[1][ct] = __builtin_amdgcn_mfma_f32_16x16x32_f16(a1, bf, acc[1][ct], 0, 0, 0);
        }
    }

    // epilogue: scale by dinv, repack through this wave's own sX rows
#pragma unroll
    for (int rt = 0; rt < 2; ++rt) {
#pragma unroll
        for (int r = 0; r < 4; ++r) {
            int lrow = w * 32 + rt * 16 + lg * 4 + r;   // D row = (lane>>4)*4 + reg
            int grow = row0 + lrow;
            float di = (grow < N) ? dinv[grow] : 0.f;
#pragma unroll
            for (int ct = 0; ct < 8; ++ct)
                sX[lrow * 136 + ct * 16 + lm] = (f16)(acc[rt][ct][r] * di);  // D col = lane&15
        }
    }
#pragma unroll
    for (int it = 0; it < 8; ++it) {
        int i = l + 64 * it;
        int lr = i >> 4, k8 = (i & 15) * 8;
        int grow = row0 + w * 32 + lr;
        if (grow < N)
            *(half8*)&hh[(size_t)grow * 128 + k8] =
                *(const half8*)&sX[(w * 32 + lr) * 136 + k8];
    }
}

// ---------- gather-aggregate: 1 wave/node, SPLIT-WAVE: 2 edges per step ----------
// Each half-wave (32 lanes) covers 128 dims at 4 fp16 (8B) per lane for ITS edge.
// 4 steps unrolled -> 8 edges in flight. Cross-half combine via shfl_xor(32).
// out[i] = relu( dinv_i * ( sum_j w_j*h'[src_j] + h'_i ) + b ),  h' = dinv*h
__global__ __launch_bounds__(256) void k_aggregate(const int2* __restrict__ srcval,
                                                   const int* __restrict__ rp4,
                                                   const f16* __restrict__ hh,
                                                   const float* __restrict__ dinv,
                                                   const float* __restrict__ b,
                                                   float* __restrict__ out, int N) {
    int node = blockIdx.x * 4 + (threadIdx.x >> 6);
    if (node >= N) return;
    int lane = threadIdx.x & 63;
    int hf = lane >> 5;                   // 0 or 1: which edge of the pair
    int d0 = (lane & 31) * 4;             // this lane's 4 dims
    int beg = rp4[node * REPS], end = rp4[(node + 1) * REPS];

    float a0x = 0.f, a0y = 0.f, a0z = 0.f, a0w = 0.f;
    float a1x = 0.f, a1y = 0.f, a1z = 0.f, a1w = 0.f;
    float a2x = 0.f, a2y = 0.f, a2z = 0.f, a2w = 0.f;
    float a3x = 0.f, a3y = 0.f, a3z = 0.f, a3w = 0.f;

    int j = beg;
    for (; j + 8 <= end; j += 8) {
        int2 m0 = srcval[j + 0 + hf];
        int2 m1 = srcval[j + 2 + hf];
        int2 m2 = srcval[j + 4 + hf];
        int2 m3 = srcval[j + 6 + hf];
        half4v v0 = *(const half4v*)&hh[(size_t)m0.x * 128 + d0];
        half4v v1 = *(const half4v*)&hh[(size_t)m1.x * 128 + d0];
        half4v v2 = *(const half4v*)&hh[(size_t)m2.x * 128 + d0];
        half4v v3 = *(const half4v*)&hh[(size_t)m3.x * 128 + d0];
        float w0 = __int_as_float(m0.y), w1 = __int_as_float(m1.y);
        float w2 = __int_as_float(m2.y), w3 = __int_as_float(m3.y);
        a0x = fmaf((float)v0[0], w0, a0x); a0y = fmaf((float)v0[1], w0, a0y);
        a0z = fmaf((float)v0[2], w0, a0z); a0w = fmaf((float)v0[3], w0, a0w);
        a1x = fmaf((float)v1[0], w1, a1x); a1y = fmaf((float)v1[1], w1, a1y);
        a1z = fmaf((float)v1[2], w1, a1z); a1w = fmaf((float)v1[3], w1, a1w);
        a2x = fmaf((float)v2[0], w2, a2x); a2y = fmaf((float)v2[1], w2, a2y);
        a2z = fmaf((float)v2[2], w2, a2z); a2w = fmaf((float)v2[3], w2, a2w);
        a3x = fmaf((float)v3[0], w3, a3x); a3y = fmaf((float)v3[1], w3, a3y);
        a3z = fmaf((float)v3[2], w3, a3z); a3w = fmaf((float)v3[3], w3, a3w);
    }
    for (; j + 2 <= end; j += 2) {
        int2 m0 = srcval[j + hf];
        float w0 = __int_as_float(m0.y);
        half4v v0 = *(const half4v*)&hh[(size_t)m0.x * 128 + d0];
        a0x = fmaf((float)v0[0], w0, a0x); a0y = fmaf((float)v0[1], w0, a0y);
        a0z = fmaf((float)v0[2], w0, a0z); a0w = fmaf((float)v0[3], w0, a0w);
    }
    if (j < end) {                        // odd leftover: half 0 only
        int2 m0 = srcval[j];
        float w0 = hf ? 0.f : __int_as_float(m0.y);
        half4v v0 = *(const half4v*)&hh[(size_t)m0.x * 128 + d0];
        a0x = fmaf((float)v0[0], w0, a0x); a0y = fmaf((float)v0[1], w0, a0y);
        a0z = fmaf((float)v0[2], w0, a0z); a0w = fmaf((float)v0[3], w0, a0w);
    }

    float sx = a0x + a1x + a2x + a3x;
    float sy = a0y + a1y + a2y + a3y;
    float sz = a0z + a1z + a2z + a3z;
    float sw = a0w + a1w + a2w + a3w;
    sx += __shfl_xor(sx, 32);
    sy += __shfl_xor(sy, 32);
    sz += __shfl_xor(sz, 32);
    sw += __shfl_xor(sw, 32);

    if (hf == 0) {
        float di = dinv[node];
        half4v hs = *(const half4v*)&hh[(size_t)node * 128 + d0];
        float4 bv = *(const float4*)&b[d0];
        float4 v;
        v.x = fmaxf(fmaf(sx + (float)hs[0], di, bv.x), 0.f);
        v.y = fmaxf(fmaf(sy + (float)hs[1], di, bv.y), 0.f);
        v.z = fmaxf(fmaf(sz + (float)hs[2], di, bv.z), 0.f);
        v.w = fmaxf(fmaf(sw + (float)hs[3], di, bv.w), 0.f);
        *(float4*)&out[(size_t)node * 128 + d0] = v;
    }
}

// ---------- pool: one block per graph, bounds by binary search, no atomics ----------
__global__ __launch_bounds__(256) void k_pool(const float* __restrict__ out,
                                              const int* __restrict__ batch,
                                              float* __restrict__ pool, int N, int G) {
    __shared__ float sacc[256];
    __shared__ int bounds[2];
    int g = blockIdx.x;
    int t = threadIdx.x;
    if (t < 2) {
        int target = g + t;
        int lo = 0, hi = N;
        while (lo < hi) {
            int mid = (lo + hi) >> 1;
            if (batch[mid] < target) lo = mid + 1; else hi = mid;
        }
        bounds[t] = lo;
    }
    __syncthreads();
    int lo = bounds[0], hi = bounds[1];
    int d = t & 127, r = t >> 7;
    float s = 0.f;
    for (int n = lo + r; n < hi; n += 2)
        s += out[(size_t)n * 128 + d];
    sacc[t] = s;
    __syncthreads();
    if (t < 128) {
        float tot = sacc[t] + sacc[t + 128];
        pool[(size_t)g * 128 + t] = tot / fmaxf((float)(hi - lo), 1.0f);
    }
}

extern "C" void kernel_launch(void* const* d_in, const int* in_sizes, int n_in,
                              void* d_out, int out_size, void* d_ws, size_t ws_size,
                              hipStream_t stream) {
    const float* x     = (const float*)d_in[0];
    const int*   ei    = (const int*)d_in[1];
    const float* ew    = (const float*)d_in[2];
    const int*   batch = (const int*)d_in[3];
    const float* W     = (const float*)d_in[4];
    const float* b     = (const float*)d_in[5];

    int N = in_sizes[3];                  // 50000
    int E = in_sizes[2];                  // 800000
    int G = (out_size - N * 128) / 128;   // 500
    int M = N * REPS;
    int nb1 = (M + 255) / 256;

    float* out  = (float*)d_out;
    float* pool = out + (size_t)N * 128;

    // workspace layout (~26 MB)
    f16*    hh     = (f16*)d_ws;                        // N*128 f16   (12.8 MB)
    int2*   srcval = (int2*)(hh + (size_t)N * 128);     // E int2      (6.4 MB)
    float*  dinv   = (float*)(srcval + E);              // N f
    int*    cnt4   = (int*)(dinv + N);                  // 8N i        (1.6 MB)
    int*    rp4    = cnt4 + M;                          // 8N+1 i      (1.6 MB)
    int*    bsum   = rp4 + M + 1;                       // nb1 i
    int*    pos    = bsum + nb1;                        // E i         (3.2 MB)
    f16*    Wt     = (f16*)(pos + E);                   // 128*128 f16 (32 KB)

    int M4  = M / 4;                       // int4 chunks to zero
    int nzb = (M4 + 255) / 256;
    k_init<<<nzb + 16, 256, 0, stream>>>(cnt4, M4, nzb, W, Wt);
    k_count_pos<<<(E + 255) / 256, 256, 0, stream>>>(ei, cnt4, pos, E, N);
    k_scan1<<<nb1, 256, 0, stream>>>(cnt4, rp4, bsum, M, N);
    k_scan3<<<nb1, 256, 0, stream>>>(rp4, bsum, M, E);
    k_fill<<<(E + 255) / 256, 256, 0, stream>>>(ei, ew, rp4, pos, srcval, E);
    k_deg_csr<<<(N + 255) / 256, 256, 0, stream>>>(rp4, srcval, dinv, N);
    k_gemm<<<(N + 127) / 128, 256, 0, stream>>>(x, Wt, dinv, hh, N);
    k_aggregate<<<(N + 3) / 4, 256, 0, stream>>>(srcval, rp4, hh, dinv, b, out, N);
    k_pool<<<G, 256, 0, stream>>>(out, batch, pool, N, G);
}

// Round 10
// 150.815 us; speedup vs baseline: 8.1634x; 1.0154x over previous
//
#include <hip/hip_runtime.h>
#include <hip/hip_fp16.h>

// GCNConv + ReLU + global mean pool for MI355X (gfx950).
// Round 10: quarter-wave gather aggregate — each 16-lane group loads a full
// 128-dim fp16 row with one b128 load, so 4 edges/wave-step at 2 VMEM instrs
// (4x fewer than the 4-deep form, same cache-line traffic). 2-step unroll ->
// 8 edges in flight. Combine via shfl_xor(16/32). Rest = round-7/9 pipeline.

#define REPS 8

typedef _Float16 f16;
typedef _Float16 half8 __attribute__((ext_vector_type(8)));
typedef float f32x4 __attribute__((ext_vector_type(4)));

// ---------- fused init: zero cnt4 (int4 stores) + W -> Wt (f16 [n][k]) ----------
__global__ __launch_bounds__(256) void k_init(int* __restrict__ cnt4, int M4, int nzb,
                                              const float* __restrict__ W,
                                              f16* __restrict__ Wt) {
    int bid = blockIdx.x;
    int t = threadIdx.x;
    if (bid < nzb) {
        int i = bid * 256 + t;
        if (i < M4) ((int4*)cnt4)[i] = make_int4(0, 0, 0, 0);
    } else {
        int n = (bid - nzb) * 8 + (t >> 5);
        int k = (t & 31) * 4;
        union { f16 h[4]; uint2 u; } p;
#pragma unroll
        for (int j = 0; j < 4; ++j) p.h[j] = (f16)W[(k + j) * 128 + n];
        *(uint2*)&Wt[n * 128 + k] = p.u;
    }
}

// ---------- count + record insertion position (1 atomic/edge, 8-way spread) ----------
__global__ __launch_bounds__(256) void k_count_pos(const int* __restrict__ ei,
                                                   int* cnt4, int* __restrict__ pos,
                                                   int E, int N) {
    int e = blockIdx.x * 256 + threadIdx.x;
    if (e < E) pos[e] = atomicAdd(&cnt4[(e & (REPS - 1)) * N + ei[E + e]], 1);
}

// ---------- scan phase 1 over M=8N counts in view order k=(node*8+rep) ----------
__global__ __launch_bounds__(256) void k_scan1(const int* __restrict__ cnt4,
                                               int* __restrict__ rp4,
                                               int* __restrict__ bsum, int M, int N) {
    __shared__ int wsum[4];
    int t = threadIdx.x;
    int k = blockIdx.x * 256 + t;
    int v = 0;
    if (k < M) v = cnt4[(k & (REPS - 1)) * N + (k / REPS)];
    int lane = t & 63, wid = t >> 6;
    int s = v;
#pragma unroll
    for (int o = 1; o < 64; o <<= 1) {
        int u = __shfl_up(s, o);
        if (lane >= o) s += u;
    }
    if (lane == 63) wsum[wid] = s;
    __syncthreads();
    int off = 0;
#pragma unroll
    for (int w = 0; w < 4; ++w)
        if (w < wid) off += wsum[w];
    if (k < M) rp4[k] = off + s - v;      // block-local exclusive
    if (t == 255) bsum[blockIdx.x] = off + s;
}

// ---------- scan phase 2: each block reduces its own carry, adds ----------
__global__ __launch_bounds__(256) void k_scan3(int* __restrict__ rp4,
                                               const int* __restrict__ bsum,
                                               int M, int E) {
    __shared__ int wsum[4];
    int t = threadIdx.x;
    int bid = blockIdx.x;
    int s = 0;
    for (int j = t; j < bid; j += 256) s += bsum[j];
    int lane = t & 63, wid = t >> 6;
#pragma unroll
    for (int o = 1; o < 64; o <<= 1) s += __shfl_down(s, o);
    if (lane == 0) wsum[wid] = s;
    __syncthreads();
    int off = wsum[0] + wsum[1] + wsum[2] + wsum[3];
    int k = bid * 256 + t;
    if (k < M) rp4[k] += off;
    if (bid == 0 && t == 0) rp4[M] = E;   // grand total known analytically
}

// ---------- atomic-free bucket fill: srcval[slot] = (src row, raw w) ----------
__global__ __launch_bounds__(256) void k_fill(const int* __restrict__ ei,
                                              const float* __restrict__ ew,
                                              const int* __restrict__ rp4,
                                              const int* __restrict__ pos,
                                              int2* __restrict__ srcval, int E) {
    int e = blockIdx.x * 256 + threadIdx.x;
    if (e >= E) return;
    int row = ei[e];
    int col = ei[E + e];
    int slot = rp4[col * REPS + (e & (REPS - 1))] + pos[e];
    srcval[slot] = make_int2(row, __float_as_int(ew[e]));
}

// ---------- weighted degree from CSR (coalesced + LDS atomics), dinv=rsqrt ----------
__global__ __launch_bounds__(256) void k_deg_csr(const int* __restrict__ rp4,
                                                 const int2* __restrict__ srcval,
                                                 float* __restrict__ dinv, int N) {
    __shared__ float sdeg[256];
    __shared__ int srp[257];
    int t = threadIdx.x;
    int n0 = blockIdx.x * 256;
    int nn = min(256, N - n0);
    if (nn <= 0) return;
    sdeg[t] = 1.0f;                       // self-loop weight
    for (int i = t; i <= nn; i += 256) srp[i] = rp4[(n0 + i) * REPS];
    __syncthreads();
    int beg = srp[0], end = srp[nn];
    for (int j = beg + t; j < end; j += 256) {
        int2 sv = srcval[j];
        int lo = 0, hi = nn - 1;          // find node: srp[lo] <= j < srp[lo+1]
        while (lo < hi) {
            int mid = (lo + hi + 1) >> 1;
            if (srp[mid] <= j) lo = mid; else hi = mid - 1;
        }
        atomicAdd(&sdeg[lo], __int_as_float(sv.y));
    }
    __syncthreads();
    if (t < nn) dinv[n0 + t] = rsqrtf(sdeg[t]);   // deg >= 1 always
}

// ---------- h' = dinv * (x @ W) -> fp16 via MFMA, 128x128 tile per block ----------
__global__ __launch_bounds__(256) void k_gemm(const float* __restrict__ x,
                                              const f16* __restrict__ Wt,
                                              const float* __restrict__ dinv,
                                              f16* __restrict__ hh, int N) {
    __shared__ f16 sX[128 * 136];   // pad 8 halves: 2-way (free) bank conflicts
    __shared__ f16 sW[128 * 136];
    int t = threadIdx.x;
    int row0 = blockIdx.x * 128;
#pragma unroll
    for (int it = 0; it < 8; ++it) {
        int i = t + 256 * it;
        int n = i >> 4, k8 = (i & 15) * 8;
        *(half8*)&sW[n * 136 + k8] = *(const half8*)&Wt[n * 128 + k8];
    }
#pragma unroll
    for (int it = 0; it < 16; ++it) {
        int i = t + 256 * it;
        int r = i >> 5, c4 = (i & 31) * 4;
        float4 xv = make_float4(0.f, 0.f, 0.f, 0.f);
        if (row0 + r < N) xv = *(const float4*)&x[(size_t)(row0 + r) * 128 + c4];
        union { f16 h[4]; uint2 u; } p;
        p.h[0] = (f16)xv.x; p.h[1] = (f16)xv.y; p.h[2] = (f16)xv.z; p.h[3] = (f16)xv.w;
        *(uint2*)&sX[r * 136 + c4] = p.u;
    }
    __syncthreads();

    int w = t >> 6, l = t & 63;
    int lm = l & 15, lg = l >> 4;
    f32x4 acc[2][8];
#pragma unroll
    for (int rt = 0; rt < 2; ++rt)
#pragma unroll
        for (int ct = 0; ct < 8; ++ct) acc[rt][ct] = (f32x4){0.f, 0.f, 0.f, 0.f};

    int arow = w * 32 + lm;
#pragma unroll
    for (int ks = 0; ks < 4; ++ks) {
        int ko = ks * 32 + lg * 8;        // K-bijection identical for A and B
        half8 a0 = *(const half8*)&sX[arow * 136 + ko];
        half8 a1 = *(const half8*)&sX[(arow + 16) * 136 + ko];
#pragma unroll
        for (int ct = 0; ct < 8; ++ct) {
            half8 bf = *(const half8*)&sW[(ct * 16 + lm) * 136 + ko];
            acc[0][ct] = __builtin_amdgcn_mfma_f32_16x16x32_f16(a0, bf, acc[0][ct], 0, 0, 0);
            acc[1][ct] = __builtin_amdgcn_mfma_f32_16x16x32_f16(a1, bf, acc[1][ct], 0, 0, 0);
        }
    }

    // epilogue: scale by dinv, repack through this wave's own sX rows
#pragma unroll
    for (int rt = 0; rt < 2; ++rt) {
#pragma unroll
        for (int r = 0; r < 4; ++r) {
            int lrow = w * 32 + rt * 16 + lg * 4 + r;   // D row = (lane>>4)*4 + reg
            int grow = row0 + lrow;
            float di = (grow < N) ? dinv[grow] : 0.f;
#pragma unroll
            for (int ct = 0; ct < 8; ++ct)
                sX[lrow * 136 + ct * 16 + lm] = (f16)(acc[rt][ct][r] * di);  // D col = lane&15
        }
    }
#pragma unroll
    for (int it = 0; it < 8; ++it) {
        int i = l + 64 * it;
        int lr = i >> 4, k8 = (i & 15) * 8;
        int grow = row0 + w * 32 + lr;
        if (grow < N)
            *(half8*)&hh[(size_t)grow * 128 + k8] =
                *(const half8*)&sX[(w * 32 + lr) * 136 + k8];
    }
}

// ---------- gather-aggregate: 1 wave/node, QUARTER-WAVE: 4 edges per step ----------
// Each 16-lane group g covers all 128 dims (half8 = 16B/lane) for edge j+g.
// 2-step unroll -> 8 edges in flight with 4 VMEM instrs. Combine: shfl_xor 16/32.
// out[i] = relu( dinv_i * ( sum_j w_j*h'[src_j] + h'_i ) + b ),  h' = dinv*h
__global__ __launch_bounds__(256) void k_aggregate(const int2* __restrict__ srcval,
                                                   const int* __restrict__ rp4,
                                                   const f16* __restrict__ hh,
                                                   const float* __restrict__ dinv,
                                                   const float* __restrict__ b,
                                                   float* __restrict__ out, int N) {
    int node = blockIdx.x * 4 + (threadIdx.x >> 6);
    if (node >= N) return;
    int lane = threadIdx.x & 63;
    int g = lane >> 4;                    // edge group 0..3
    int lm = lane & 15;
    int d0 = lm * 8;                      // this lane's 8 dims
    int beg = rp4[node * REPS], end = rp4[(node + 1) * REPS];

    float acc0[8], acc1[8];
#pragma unroll
    for (int k = 0; k < 8; ++k) { acc0[k] = 0.f; acc1[k] = 0.f; }

    int j = beg;
    for (; j + 8 <= end; j += 8) {
        int2 ma = srcval[j + g];
        int2 mb = srcval[j + 4 + g];
        half8 va = *(const half8*)&hh[(size_t)ma.x * 128 + d0];
        half8 vb = *(const half8*)&hh[(size_t)mb.x * 128 + d0];
        float wa = __int_as_float(ma.y);
        float wb = __int_as_float(mb.y);
#pragma unroll
        for (int k = 0; k < 8; ++k) {
            acc0[k] = fmaf((float)va[k], wa, acc0[k]);
            acc1[k] = fmaf((float)vb[k], wb, acc1[k]);
        }
    }
    if (j + 4 <= end) {
        int2 ma = srcval[j + g];
        half8 va = *(const half8*)&hh[(size_t)ma.x * 128 + d0];
        float wa = __int_as_float(ma.y);
#pragma unroll
        for (int k = 0; k < 8; ++k) acc0[k] = fmaf((float)va[k], wa, acc0[k]);
        j += 4;
    }
    int r = end - j;                      // 0..3 leftover edges
    if (r > 0) {
        int2 ma = srcval[j + min(g, r - 1)];
        float wa = (g < r) ? __int_as_float(ma.y) : 0.f;
        half8 va = *(const half8*)&hh[(size_t)ma.x * 128 + d0];
#pragma unroll
        for (int k = 0; k < 8; ++k) acc0[k] = fmaf((float)va[k], wa, acc0[k]);
    }

#pragma unroll
    for (int k = 0; k < 8; ++k) acc0[k] += acc1[k];
#pragma unroll
    for (int k = 0; k < 8; ++k) acc0[k] += __shfl_xor(acc0[k], 16);
#pragma unroll
    for (int k = 0; k < 8; ++k) acc0[k] += __shfl_xor(acc0[k], 32);

    if (g == 0) {                         // lanes 0..15 finish + store 512B row
        float di = dinv[node];
        half8 hs = *(const half8*)&hh[(size_t)node * 128 + d0];
        float4 bv0 = *(const float4*)&b[d0];
        float4 bv1 = *(const float4*)&b[d0 + 4];
        float4 o0, o1;
        o0.x = fmaxf(fmaf(acc0[0] + (float)hs[0], di, bv0.x), 0.f);
        o0.y = fmaxf(fmaf(acc0[1] + (float)hs[1], di, bv0.y), 0.f);
        o0.z = fmaxf(fmaf(acc0[2] + (float)hs[2], di, bv0.z), 0.f);
        o0.w = fmaxf(fmaf(acc0[3] + (float)hs[3], di, bv0.w), 0.f);
        o1.x = fmaxf(fmaf(acc0[4] + (float)hs[4], di, bv1.x), 0.f);
        o1.y = fmaxf(fmaf(acc0[5] + (float)hs[5], di, bv1.y), 0.f);
        o1.z = fmaxf(fmaf(acc0[6] + (float)hs[6], di, bv1.z), 0.f);
        o1.w = fmaxf(fmaf(acc0[7] + (float)hs[7], di, bv1.w), 0.f);
        *(float4*)&out[(size_t)node * 128 + d0] = o0;
        *(float4*)&out[(size_t)node * 128 + d0 + 4] = o1;
    }
}

// ---------- pool: one block per graph, bounds by binary search, no atomics ----------
__global__ __launch_bounds__(256) void k_pool(const float* __restrict__ out,
                                              const int* __restrict__ batch,
                                              float* __restrict__ pool, int N, int G) {
    __shared__ float sacc[256];
    __shared__ int bounds[2];
    int g = blockIdx.x;
    int t = threadIdx.x;
    if (t < 2) {
        int target = g + t;
        int lo = 0, hi = N;
        while (lo < hi) {
            int mid = (lo + hi) >> 1;
            if (batch[mid] < target) lo = mid + 1; else hi = mid;
        }
        bounds[t] = lo;
    }
    __syncthreads();
    int lo = bounds[0], hi = bounds[1];
    int d = t & 127, r = t >> 7;
    float s = 0.f;
    for (int n = lo + r; n < hi; n += 2)
        s += out[(size_t)n * 128 + d];
    sacc[t] = s;
    __syncthreads();
    if (t < 128) {
        float tot = sacc[t] + sacc[t + 128];
        pool[(size_t)g * 128 + t] = tot / fmaxf((float)(hi - lo), 1.0f);
    }
}

extern "C" void kernel_launch(void* const* d_in, const int* in_sizes, int n_in,
                              void* d_out, int out_size, void* d_ws, size_t ws_size,
                              hipStream_t stream) {
    const float* x     = (const float*)d_in[0];
    const int*   ei    = (const int*)d_in[1];
    const float* ew    = (const float*)d_in[2];
    const int*   batch = (const int*)d_in[3];
    const float* W     = (const float*)d_in[4];
    const float* b     = (const float*)d_in[5];

    int N = in_sizes[3];                  // 50000
    int E = in_sizes[2];                  // 800000
    int G = (out_size - N * 128) / 128;   // 500
    int M = N * REPS;
    int nb1 = (M + 255) / 256;

    float* out  = (float*)d_out;
    float* pool = out + (size_t)N * 128;

    // workspace layout (~26 MB)
    f16*    hh     = (f16*)d_ws;                        // N*128 f16   (12.8 MB)
    int2*   srcval = (int2*)(hh + (size_t)N * 128);     // E int2      (6.4 MB)
    float*  dinv   = (float*)(srcval + E);              // N f
    int*    cnt4   = (int*)(dinv + N);                  // 8N i        (1.6 MB)
    int*    rp4    = cnt4 + M;                          // 8N+1 i      (1.6 MB)
    int*    bsum   = rp4 + M + 1;                       // nb1 i
    int*    pos    = bsum + nb1;                        // E i         (3.2 MB)
    f16*    Wt     = (f16*)(pos + E);                   // 128*128 f16 (32 KB)

    int M4  = M / 4;                       // int4 chunks to zero
    int nzb = (M4 + 255) / 256;
    k_init<<<nzb + 16, 256, 0, stream>>>(cnt4, M4, nzb, W, Wt);
    k_count_pos<<<(E + 255) / 256, 256, 0, stream>>>(ei, cnt4, pos, E, N);
    k_scan1<<<nb1, 256, 0, stream>>>(cnt4, rp4, bsum, M, N);
    k_scan3<<<nb1, 256, 0, stream>>>(rp4, bsum, M, E);
    k_fill<<<(E + 255) / 256, 256, 0, stream>>>(ei, ew, rp4, pos, srcval, E);
    k_deg_csr<<<(N + 255) / 256, 256, 0, stream>>>(rp4, srcval, dinv, N);
    k_gemm<<<(N + 127) / 128, 256, 0, stream>>>(x, Wt, dinv, hh, N);
    k_aggregate<<<(N + 3) / 4, 256, 0, stream>>>(srcval, rp4, hh, dinv, b, out, N);
    k_pool<<<G, 256, 0, stream>>>(out, batch, pool, N, G);
}